// Round 6
// baseline (1564.028 us; speedup 1.0000x reference)
//
#include <hip/hip_runtime.h>
#include <cstdint>
#include <cstddef>

// ---------------------------------------------------------------------------
// GCN 2-layer, N=100k nodes, E=1.6M edges, F=64, fp32 in/out.
//
//   deg[n] accumulated in k_bscatter (global int atomics, native)
//   dis(n) = rsqrt(deg+1) recomputed at use (bitwise-identical everywhere)
//   g   = bf16( (X @ W1) * dis[row] )   GEMM via MFMA, split-bf16 x3
//   h   = relu( dis * (agg g) + b1 )    bucket-direct agg in LDS
//   g'  = bf16( (h @ W2) * dis )        fused MFMA epilogue in aggb1
//   out = dis * (agg g') + b2           bucket-direct agg + epilogue
//
// R6: R5's bucket-direct structure was correct (absmax bit-identical) but
// atomicAdd(float*) on LDS lowers to a CAS retry loop without
// -munsafe-fp-atomics -> 714 us with all pipes idle (DS pipe retry storm,
// VGPR 32). Fix: unsafeAtomicAdd -> native ds_add_f32 (fire-and-forget,
// pipelined). Also: gcursor -> zeroed count array + deg[] accumulated in
// bscatter; k_init/k_count deleted (5 dispatches total; one memset).
// R3 lesson kept: MFMA epilogue fusion. R2/R4: no manual gather pipelining,
// CSR-side tweaks dead end. R1: keep agg-phase VGPR low.
// ---------------------------------------------------------------------------

#define BK_SHIFT 8                 // 256 nodes per bucket
#define BK_NODES 256
#define EPB 8192                   // edges per scatter block (long runs)
#define CAP 5376                   // padded bucket capacity (mean 4096 + 20s)
#define NBMAX 512                  // max buckets (N<=131072 -> NB<=512)
#define ACCW 67                    // LDS accumulator row stride (odd)

typedef short bf16x8 __attribute__((ext_vector_type(8)));
typedef float f32x4  __attribute__((ext_vector_type(4)));

static __device__ __forceinline__ unsigned short f2b(float f) {
    unsigned x = __float_as_uint(f);
    unsigned r = (x + 0x7FFFu + ((x >> 16) & 1u)) >> 16;   // RNE
    return (unsigned short)r;
}
static __device__ __forceinline__ float blo(unsigned u) {
    return __uint_as_float(u << 16);
}
static __device__ __forceinline__ float bhi(unsigned u) {
    return __uint_as_float(u & 0xFFFF0000u);
}
static __device__ __forceinline__ void splitbf(float x, short& hi, short& lo) {
    unsigned short h = f2b(x);
    hi = (short)h;
    float r = x - __uint_as_float((unsigned)h << 16);
    lo = (short)f2b(r);
}
// native LDS fp32 add (ds_add_f32, fire-and-forget) -- NOT plain atomicAdd,
// which compiles to a CAS retry loop (R5: 714 us).
static __device__ __forceinline__ void lds_add(float* p, float v) {
    unsafeAtomicAdd(p, v);
}

// ---- scatter edges into padded bucket windows + deg accumulation ----------
// pack = src (17 bits) | dst_local (8 bits) << 17   (N <= 131072)
// gcount[] zero-initialized; window position = b*CAP + atomic count.
__global__ void __launch_bounds__(256) k_bscatter(const int* __restrict__ src,
                                                  const int* __restrict__ dst,
                                                  int* __restrict__ gcount,
                                                  int* __restrict__ deg,
                                                  unsigned* __restrict__ packed,
                                                  int E, int NB) {
    __shared__ int hist[NBMAX];
    __shared__ int base[NBMAX];
    int t = threadIdx.x;
    for (int i = t; i < NB; i += 256) hist[i] = 0;
    __syncthreads();
    int e0 = blockIdx.x * EPB;
    int e1 = min(e0 + EPB, E);
    // phase 1: block histogram + global deg atomics (both fire-and-forget)
    int4 dv[8];
    int kd[8];
#pragma unroll
    for (int k = 0; k < 8; ++k) {
        int e = e0 + t * 4 + k * 1024;
        kd[k] = (e + 3 < e1) ? 1 : 0;
        if (kd[k]) dv[k] = *(const int4*)(dst + e);
    }
#pragma unroll
    for (int k = 0; k < 8; ++k) {
        if (kd[k]) {
            atomicAdd(&hist[dv[k].x >> BK_SHIFT], 1);
            atomicAdd(&hist[dv[k].y >> BK_SHIFT], 1);
            atomicAdd(&hist[dv[k].z >> BK_SHIFT], 1);
            atomicAdd(&hist[dv[k].w >> BK_SHIFT], 1);
            atomicAdd(&deg[dv[k].x], 1);
            atomicAdd(&deg[dv[k].y], 1);
            atomicAdd(&deg[dv[k].z], 1);
            atomicAdd(&deg[dv[k].w], 1);
        }
    }
    __syncthreads();
    // phase 2: reserve chunk in each bucket's padded window
    for (int i = t; i < NB; i += 256) {
        int c = hist[i];
        base[i] = i * CAP + (c ? atomicAdd(&gcount[i], c) : 0);
        hist[i] = 0;
    }
    __syncthreads();
    // phase 3: scatter (batched src loads; dst re-used from regs)
    int4 sv[8];
#pragma unroll
    for (int k = 0; k < 8; ++k) {
        int e = e0 + t * 4 + k * 1024;
        if (kd[k]) sv[k] = *(const int4*)(src + e);
    }
#pragma unroll
    for (int k = 0; k < 8; ++k) {
        if (kd[k]) {
            int b0 = dv[k].x >> BK_SHIFT;
            int p0 = base[b0] + atomicAdd(&hist[b0], 1);
            packed[p0] = (unsigned)sv[k].x | (((unsigned)dv[k].x & (BK_NODES - 1)) << 17);
            int b1 = dv[k].y >> BK_SHIFT;
            int p1 = base[b1] + atomicAdd(&hist[b1], 1);
            packed[p1] = (unsigned)sv[k].y | (((unsigned)dv[k].y & (BK_NODES - 1)) << 17);
            int b2 = dv[k].z >> BK_SHIFT;
            int p2 = base[b2] + atomicAdd(&hist[b2], 1);
            packed[p2] = (unsigned)sv[k].z | (((unsigned)dv[k].z & (BK_NODES - 1)) << 17);
            int b3 = dv[k].w >> BK_SHIFT;
            int p3 = base[b3] + atomicAdd(&hist[b3], 1);
            packed[p3] = (unsigned)sv[k].w | (((unsigned)dv[k].w & (BK_NODES - 1)) << 17);
        }
    }
}

// ---- GEMM via MFMA: g16[row] = bf16( (X[row] @ W) * rsqrt(deg+1) ) --------
// Layouts (measured, learn_hip m89/m91/m120):
//   A[m=lane&15][k=quad*8+j]   B[k=quad*8+j][n=lane&15]
//   C: col=lane&15, row=quad*4+reg
__global__ void __launch_bounds__(256) k_gemm_mfma(const float* __restrict__ X,
                                                   const float* __restrict__ W,
                                                   const int* __restrict__ deg,
                                                   unsigned short* __restrict__ g16,
                                                   int n, int nstrips) {
    __shared__ float Ws[4096];     // 64x64 fp32 = 16 KB
    int t = threadIdx.x;
    {
        const float4* W4 = (const float4*)W;
        float4* S4 = (float4*)Ws;
#pragma unroll
        for (int i = 0; i < 4; ++i) S4[t + i * 256] = W4[t + i * 256];
    }
    __syncthreads();
    int wid  = t >> 6;
    int lane = t & 63;
    int quad = lane >> 4;
    int fl   = lane & 15;

    bf16x8 Bh[4][2], Bl[4][2];
#pragma unroll
    for (int tt = 0; tt < 4; ++tt)
#pragma unroll
        for (int c = 0; c < 2; ++c)
#pragma unroll
            for (int j = 0; j < 8; ++j) {
                float w = Ws[(c * 32 + quad * 8 + j) * 64 + tt * 16 + fl];
                short hi, lo;
                splitbf(w, hi, lo);
                Bh[tt][c][j] = hi;
                Bl[tt][c][j] = lo;
            }

    for (int s = blockIdx.x * 4 + wid; s < nstrips; s += gridDim.x * 4) {
        int row0 = s << 4;
        const float4* xp = (const float4*)(X + ((size_t)(row0 + fl) << 6));
        bf16x8 Ah[2], Al[2];
#pragma unroll
        for (int c = 0; c < 2; ++c) {
            float4 a = xp[c * 8 + quad * 2];
            float4 b = xp[c * 8 + quad * 2 + 1];
            float xs[8] = {a.x, a.y, a.z, a.w, b.x, b.y, b.z, b.w};
#pragma unroll
            for (int j = 0; j < 8; ++j) {
                short hi, lo;
                splitbf(xs[j], hi, lo);
                Ah[c][j] = hi;
                Al[c][j] = lo;
            }
        }
        f32x4 acc[4];
#pragma unroll
        for (int tt = 0; tt < 4; ++tt) acc[tt] = (f32x4){0.f, 0.f, 0.f, 0.f};
#pragma unroll
        for (int tt = 0; tt < 4; ++tt) {
#pragma unroll
            for (int c = 0; c < 2; ++c) {
                acc[tt] = __builtin_amdgcn_mfma_f32_16x16x32_bf16(Ah[c], Bh[tt][c], acc[tt], 0, 0, 0);
                acc[tt] = __builtin_amdgcn_mfma_f32_16x16x32_bf16(Al[c], Bh[tt][c], acc[tt], 0, 0, 0);
                acc[tt] = __builtin_amdgcn_mfma_f32_16x16x32_bf16(Ah[c], Bl[tt][c], acc[tt], 0, 0, 0);
            }
        }
        int4 dvi = *(const int4*)(deg + row0 + quad * 4);
        float ds4[4] = {rsqrtf((float)(dvi.x + 1)), rsqrtf((float)(dvi.y + 1)),
                        rsqrtf((float)(dvi.z + 1)), rsqrtf((float)(dvi.w + 1))};
#pragma unroll
        for (int tt = 0; tt < 4; ++tt) {
#pragma unroll
            for (int r = 0; r < 4; ++r) {
                int row = row0 + quad * 4 + r;
                float v = acc[tt][r] * ds4[r];
                g16[(size_t)row * 64 + tt * 16 + fl] = f2b(v);
            }
        }
    }
}

// ---- bucket agg L1: LDS accum (ds_add_f32) -> h=relu -> MFMA h@W2 -> g16b -
__global__ void __launch_bounds__(1024, 8) k_aggb1(const unsigned short* __restrict__ g16,
                                                   const unsigned* __restrict__ packed,
                                                   const int* __restrict__ gcount,
                                                   const int* __restrict__ deg,
                                                   const float* __restrict__ bias,
                                                   const float* __restrict__ W2,
                                                   unsigned short* __restrict__ g16b,
                                                   int N) {
    __shared__ float acc[BK_NODES * ACCW];     // 67 KB
    int t = threadIdx.x;
    int b = blockIdx.x;
    int node0 = b << BK_SHIFT;
    for (int i = t; i < BK_NODES * ACCW; i += 1024) acc[i] = 0.f;
    __syncthreads();

    int e0 = b * CAP;
    int count = gcount[b];
    int lane = t & 63;
    int wv = t >> 6;                  // 0..15
    int sub = lane >> 3;
    int fl = lane & 7;
    for (int base = wv << 6; base < count; base += 1024) {
        int idx = base + lane;
        unsigned pe = (idx < count) ? packed[e0 + idx] : 0xFFFFFFFFu;
#pragma unroll
        for (int k = 0; k < 8; ++k) {
            unsigned p = __shfl(pe, k * 8 + sub);
            if (p != 0xFFFFFFFFu) {
                int srcn = (int)(p & 0x1FFFFu);
                int dl = (int)(p >> 17);
                uint4 u = *((const uint4*)(g16 + ((size_t)srcn << 6)) + fl);
                float* ap = &acc[dl * ACCW + fl * 8];
                lds_add(ap + 0, blo(u.x)); lds_add(ap + 1, bhi(u.x));
                lds_add(ap + 2, blo(u.y)); lds_add(ap + 3, bhi(u.y));
                lds_add(ap + 4, blo(u.z)); lds_add(ap + 5, bhi(u.z));
                lds_add(ap + 6, blo(u.w)); lds_add(ap + 7, bhi(u.w));
            }
        }
    }
    __syncthreads();

    // transform in place: acc -> h = relu(dis*(acc+self)+b1)
    {
        int row = t >> 2;              // 0..255
        int fg = (t & 3) << 4;         // 0,16,32,48
        int node = node0 + row;
        float* ap = &acc[row * ACCW + fg];
        if (node < N) {
            float s = rsqrtf((float)(deg[node] + 1));
            const uint4* sp = (const uint4*)(g16 + ((size_t)node << 6)) + ((t & 3) << 1);
            uint4 u0 = sp[0], u1 = sp[1];
            float sv[16];
            sv[0] = blo(u0.x); sv[1] = bhi(u0.x); sv[2] = blo(u0.y); sv[3] = bhi(u0.y);
            sv[4] = blo(u0.z); sv[5] = bhi(u0.z); sv[6] = blo(u0.w); sv[7] = bhi(u0.w);
            sv[8] = blo(u1.x); sv[9] = bhi(u1.x); sv[10] = blo(u1.y); sv[11] = bhi(u1.y);
            sv[12] = blo(u1.z); sv[13] = bhi(u1.z); sv[14] = blo(u1.w); sv[15] = bhi(u1.w);
#pragma unroll
            for (int j = 0; j < 16; ++j)
                ap[j] = fmaxf(fmaf(s, ap[j] + sv[j], bias[fg + j]), 0.f);
        } else {
#pragma unroll
            for (int j = 0; j < 16; ++j) ap[j] = 0.f;
        }
    }
    __syncthreads();

    // MFMA epilogue: rows [wv*16, wv*16+16) of (h @ W2) * dis -> bf16
    {
        int quad = lane >> 4;
        int fq = lane & 15;
        const float* hrow = &acc[((wv << 4) + fq) * ACCW];
        bf16x8 Ah[2], Al[2];
#pragma unroll
        for (int kc = 0; kc < 2; ++kc)
#pragma unroll
            for (int j = 0; j < 8; ++j) {
                short hi, lo;
                splitbf(hrow[kc * 32 + quad * 8 + j], hi, lo);
                Ah[kc][j] = hi;
                Al[kc][j] = lo;
            }
        int row0 = node0 + (wv << 4) + (quad << 2);
        float d4[4];
#pragma unroll
        for (int r = 0; r < 4; ++r) {
            int rr = row0 + r;
            d4[r] = (rr < N) ? rsqrtf((float)(deg[rr] + 1)) : 0.f;
        }
#pragma unroll
        for (int tt = 0; tt < 4; ++tt) {
            bf16x8 Bh[2], Bl[2];
#pragma unroll
            for (int kc = 0; kc < 2; ++kc)
#pragma unroll
                for (int j = 0; j < 8; ++j) {
                    short hi, lo;
                    splitbf(W2[(kc * 32 + quad * 8 + j) * 64 + tt * 16 + fq], hi, lo);
                    Bh[kc][j] = hi;
                    Bl[kc][j] = lo;
                }
            f32x4 a = (f32x4){0.f, 0.f, 0.f, 0.f};
#pragma unroll
            for (int kc = 0; kc < 2; ++kc) {
                a = __builtin_amdgcn_mfma_f32_16x16x32_bf16(Ah[kc], Bh[kc], a, 0, 0, 0);
                a = __builtin_amdgcn_mfma_f32_16x16x32_bf16(Al[kc], Bh[kc], a, 0, 0, 0);
                a = __builtin_amdgcn_mfma_f32_16x16x32_bf16(Ah[kc], Bl[kc], a, 0, 0, 0);
            }
#pragma unroll
            for (int r = 0; r < 4; ++r) {
                int row = row0 + r;
                if (row < N)
                    g16b[(size_t)row * 64 + tt * 16 + fq] = f2b(a[r] * d4[r]);
            }
        }
    }
}

// ---- bucket agg L2: LDS accum -> out = dis*(acc+self)+b2 (fp32) -----------
__global__ void __launch_bounds__(1024, 8) k_aggb2(const unsigned short* __restrict__ g16b,
                                                   const unsigned* __restrict__ packed,
                                                   const int* __restrict__ gcount,
                                                   const int* __restrict__ deg,
                                                   const float* __restrict__ bias,
                                                   float* __restrict__ out,
                                                   int N) {
    __shared__ float acc[BK_NODES * ACCW];     // 67 KB
    int t = threadIdx.x;
    int b = blockIdx.x;
    int node0 = b << BK_SHIFT;
    for (int i = t; i < BK_NODES * ACCW; i += 1024) acc[i] = 0.f;
    __syncthreads();

    int e0 = b * CAP;
    int count = gcount[b];
    int lane = t & 63;
    int wv = t >> 6;
    int sub = lane >> 3;
    int fl = lane & 7;
    for (int base = wv << 6; base < count; base += 1024) {
        int idx = base + lane;
        unsigned pe = (idx < count) ? packed[e0 + idx] : 0xFFFFFFFFu;
#pragma unroll
        for (int k = 0; k < 8; ++k) {
            unsigned p = __shfl(pe, k * 8 + sub);
            if (p != 0xFFFFFFFFu) {
                int srcn = (int)(p & 0x1FFFFu);
                int dl = (int)(p >> 17);
                uint4 u = *((const uint4*)(g16b + ((size_t)srcn << 6)) + fl);
                float* ap = &acc[dl * ACCW + fl * 8];
                lds_add(ap + 0, blo(u.x)); lds_add(ap + 1, bhi(u.x));
                lds_add(ap + 2, blo(u.y)); lds_add(ap + 3, bhi(u.y));
                lds_add(ap + 4, blo(u.z)); lds_add(ap + 5, bhi(u.z));
                lds_add(ap + 6, blo(u.w)); lds_add(ap + 7, bhi(u.w));
            }
        }
    }
    __syncthreads();

    {
        int row = t >> 2;
        int fg = (t & 3) << 4;
        int node = node0 + row;
        if (node < N) {
            float s = rsqrtf((float)(deg[node] + 1));
            const uint4* sp = (const uint4*)(g16b + ((size_t)node << 6)) + ((t & 3) << 1);
            uint4 u0 = sp[0], u1 = sp[1];
            float sv[16];
            sv[0] = blo(u0.x); sv[1] = bhi(u0.x); sv[2] = blo(u0.y); sv[3] = bhi(u0.y);
            sv[4] = blo(u0.z); sv[5] = bhi(u0.z); sv[6] = blo(u0.w); sv[7] = bhi(u0.w);
            sv[8] = blo(u1.x); sv[9] = bhi(u1.x); sv[10] = blo(u1.y); sv[11] = bhi(u1.y);
            sv[12] = blo(u1.z); sv[13] = bhi(u1.z); sv[14] = blo(u1.w); sv[15] = bhi(u1.w);
            const float* ap = &acc[row * ACCW + fg];
            float o[16];
#pragma unroll
            for (int j = 0; j < 16; ++j)
                o[j] = fmaf(s, ap[j] + sv[j], bias[fg + j]);
            float4* op = (float4*)(out + ((size_t)node << 6) + fg);
            op[0] = (float4){o[0], o[1], o[2], o[3]};
            op[1] = (float4){o[4], o[5], o[6], o[7]};
            op[2] = (float4){o[8], o[9], o[10], o[11]};
            op[3] = (float4){o[12], o[13], o[14], o[15]};
        }
    }
}

extern "C" void kernel_launch(void* const* d_in, const int* in_sizes, int n_in,
                              void* d_out, int out_size, void* d_ws, size_t ws_size,
                              hipStream_t stream) {
    const float* x  = (const float*)d_in[0];
    const int*   ei = (const int*)d_in[1];
    const float* W1 = (const float*)d_in[2];
    const float* b1 = (const float*)d_in[3];
    const float* W2 = (const float*)d_in[4];
    const float* b2 = (const float*)d_in[5];
    float* out = (float*)d_out;

    const int N = in_sizes[0] / 64;
    const int E = in_sizes[1] / 2;
    const int NB = (N + BK_NODES - 1) >> BK_SHIFT;
    const int nstrips = (N + 15) >> 4;
    const int* src = ei;
    const int* dst = ei + E;

    char* ws = (char*)d_ws;
    size_t off = 0;
    auto alloc = [&](size_t bytes) -> void* {
        void* p = ws + off;
        off = (off + bytes + 255) & ~(size_t)255;
        return p;
    };
    // gcount + deg contiguous -> single memset
    int*            zbase   = (int*)alloc((size_t)(NBMAX + N) * 4);
    int*            gcount  = zbase;
    int*            deg     = zbase + NBMAX;
    unsigned*       packed  = (unsigned*)alloc((size_t)NB * CAP * 4);
    unsigned short* g16     = (unsigned short*)alloc((size_t)N * 64 * 2);
    unsigned short* g16b    = (unsigned short*)alloc((size_t)N * 64 * 2);
    (void)ws_size;

    hipMemsetAsync(zbase, 0, (size_t)(NBMAX + N) * 4, stream);
    k_bscatter<<<(E + EPB - 1) / EPB, 256, 0, stream>>>(src, dst, gcount, deg, packed, E, NB);
    k_gemm_mfma<<<782, 256, 0, stream>>>(x, W1, deg, g16, N, nstrips);
    k_aggb1<<<NB, 1024, 0, stream>>>(g16, packed, gcount, deg, b1, W2, g16b, N);
    k_aggb2<<<NB, 1024, 0, stream>>>(g16b, packed, gcount, deg, b2, out, N);
}

// Round 8
// 335.382 us; speedup vs baseline: 4.6634x; 4.6634x over previous
//
#include <hip/hip_runtime.h>
#include <cstdint>
#include <cstddef>

// ---------------------------------------------------------------------------
// GCN 2-layer, N=100k nodes, E=1.6M edges, F=64, fp32 in/out.
//
//   dis[n] = rsqrt(in_deg[n]+1)            (self-loop folded in analytically)
//   g = bf16( (X @ W1) * dis[row] )        GEMM via MFMA, split-bf16 x3
//   h = relu( dis * (gather-sum g) + b1 )  4-pass feature-split gather (R7)
//   g' = bf16( (h @ W2) * dis )            fused MFMA epilogue (R3)
//   out = dis * (gather-sum g') + b2       4-pass feature-split gather
//
// R8 = R7 with the template-syntax compile error fixed (k_agg is a plain
// kernel now; launch without <0>).
// R7 theory: aggs were re-read-traffic bound: FETCH_SIZE 83 MB vs ~20 MB
// compulsory (R3 counters) -- 205 MB of random 128B row re-reads thrash the
// 4MB/XCD L2. Gather now runs 4 passes over the edge list, each touching a
// 32B feature slice of g16 (3.2 MB -> L2-RESIDENT per XCD; re-reads become
// L2 hits). col re-read 4x with nontemporal loads; out written nontemporal.
// Per-feature accumulation order identical to R3 -> bitwise-same absmax.
// R5/R6 lesson: LDS fp32 atomics are a CAS retry storm at HIP level --
// bucket-direct agg abandoned. R2: no manual gather pipelining. R1: keep
// agg VGPR low (epilogue regs must not overlap gather regs).
// ---------------------------------------------------------------------------

#define BK_SHIFT 9                 // 512 nodes per bucket
#define BK_NODES 512
#define EPB 8192                   // edges per scatter block
#define CAP 12288                  // padded bucket capacity (slots)
#define NBMAX 256                  // max buckets (N<=131072 -> NB<=256)

typedef short bf16x8 __attribute__((ext_vector_type(8)));
typedef float f32x4  __attribute__((ext_vector_type(4)));
typedef float f32x2  __attribute__((ext_vector_type(2)));

static __device__ __forceinline__ unsigned short f2b(float f) {
    unsigned x = __float_as_uint(f);
    unsigned r = (x + 0x7FFFu + ((x >> 16) & 1u)) >> 16;   // RNE
    return (unsigned short)r;
}
static __device__ __forceinline__ float blo(unsigned u) {
    return __uint_as_float(u << 16);
}
static __device__ __forceinline__ float bhi(unsigned u) {
    return __uint_as_float(u & 0xFFFF0000u);
}
static __device__ __forceinline__ void splitbf(float x, short& hi, short& lo) {
    unsigned short h = f2b(x);
    hi = (short)h;
    float r = x - __uint_as_float((unsigned)h << 16);
    lo = (short)f2b(r);
}

// ---- init: gcursor[b] = b*CAP --------------------------------------------
__global__ void k_init(int* __restrict__ gcursor, int NB) {
    int t = threadIdx.x;
    if (t < NB) gcursor[t] = t * CAP;
}

// ---- scatter edges into padded bucket windows, packed uint32 --------------
// pack = src (17 bits) | dst_local (9 bits) << 17   (N <= 131072)
__global__ void __launch_bounds__(256) k_bscatter(const int* __restrict__ src,
                                                  const int* __restrict__ dst,
                                                  int* __restrict__ gcursor,
                                                  unsigned* __restrict__ packed,
                                                  int E, int NB) {
    __shared__ int hist[NBMAX];
    __shared__ int base[NBMAX];
    int t = threadIdx.x;
    for (int i = t; i < NB; i += 256) hist[i] = 0;
    __syncthreads();
    int e0 = blockIdx.x * EPB;
    int e1 = min(e0 + EPB, E);
    int4 dv[8];
    int kd[8];
#pragma unroll
    for (int k = 0; k < 8; ++k) {
        int e = e0 + t * 4 + k * 1024;
        kd[k] = (e + 3 < e1) ? 1 : 0;
        if (kd[k]) dv[k] = *(const int4*)(dst + e);
    }
#pragma unroll
    for (int k = 0; k < 8; ++k) {
        if (kd[k]) {
            atomicAdd(&hist[dv[k].x >> BK_SHIFT], 1);
            atomicAdd(&hist[dv[k].y >> BK_SHIFT], 1);
            atomicAdd(&hist[dv[k].z >> BK_SHIFT], 1);
            atomicAdd(&hist[dv[k].w >> BK_SHIFT], 1);
        }
    }
    __syncthreads();
    for (int i = t; i < NB; i += 256) {
        int c = hist[i];
        base[i] = c ? atomicAdd(&gcursor[i], c) : 0;
        hist[i] = 0;
    }
    __syncthreads();
    int4 sv[8];
#pragma unroll
    for (int k = 0; k < 8; ++k) {
        int e = e0 + t * 4 + k * 1024;
        if (kd[k]) sv[k] = *(const int4*)(src + e);
    }
#pragma unroll
    for (int k = 0; k < 8; ++k) {
        if (kd[k]) {
            int b0 = dv[k].x >> BK_SHIFT;
            int p0 = base[b0] + atomicAdd(&hist[b0], 1);
            packed[p0] = (unsigned)sv[k].x | (((unsigned)dv[k].x & (BK_NODES - 1)) << 17);
            int b1 = dv[k].y >> BK_SHIFT;
            int p1 = base[b1] + atomicAdd(&hist[b1], 1);
            packed[p1] = (unsigned)sv[k].y | (((unsigned)dv[k].y & (BK_NODES - 1)) << 17);
            int b2 = dv[k].z >> BK_SHIFT;
            int p2 = base[b2] + atomicAdd(&hist[b2], 1);
            packed[p2] = (unsigned)sv[k].z | (((unsigned)dv[k].z & (BK_NODES - 1)) << 17);
            int b3 = dv[k].w >> BK_SHIFT;
            int p3 = base[b3] + atomicAdd(&hist[b3], 1);
            packed[p3] = (unsigned)sv[k].w | (((unsigned)dv[k].w & (BK_NODES - 1)) << 17);
        }
    }
}

// ---- per-bucket CSR build (one block of 512 per bucket) -------------------
__global__ void __launch_bounds__(512) k_build(const unsigned* __restrict__ packed,
                                               const int* __restrict__ gcursor,
                                               int* __restrict__ rp,
                                               int* __restrict__ dega,
                                               float* __restrict__ dis,
                                               int* __restrict__ col, int N) {
    __shared__ int cnt_s[BK_NODES];
    __shared__ int tmp[BK_NODES];
    int b = blockIdx.x;
    int t = threadIdx.x;
    int node0 = b << BK_SHIFT;
    int nnode = min(BK_NODES, N - node0);
    int e0 = b * CAP;
    int e1 = gcursor[b];               // final cursor = e0 + count
    cnt_s[t] = 0;
    __syncthreads();
    for (int e = e0 + t * 4; e < e1; e += 2048) {
        int m = e1 - e; m = m > 4 ? 4 : m;
        unsigned p0 = packed[e];
        unsigned p1 = (m > 1) ? packed[e + 1] : 0;
        unsigned p2 = (m > 2) ? packed[e + 2] : 0;
        unsigned p3 = (m > 3) ? packed[e + 3] : 0;
        atomicAdd(&cnt_s[p0 >> 17], 1);
        if (m > 1) atomicAdd(&cnt_s[p1 >> 17], 1);
        if (m > 2) atomicAdd(&cnt_s[p2 >> 17], 1);
        if (m > 3) atomicAdd(&cnt_s[p3 >> 17], 1);
    }
    __syncthreads();
    int v = cnt_s[t];
    tmp[t] = v;
    __syncthreads();
    for (int off = 1; off < BK_NODES; off <<= 1) {
        int a = (t >= off) ? tmp[t - off] : 0;
        __syncthreads();
        tmp[t] += a;
        __syncthreads();
    }
    int excl = tmp[t] - v;
    if (t < nnode) {
        rp[node0 + t] = e0 + excl;
        dega[node0 + t] = v;
        dis[node0 + t] = rsqrtf((float)(v + 1));
    }
    __syncthreads();
    cnt_s[t] = excl;                   // reuse as local cursor
    __syncthreads();
    for (int e = e0 + t * 4; e < e1; e += 2048) {
        int m = e1 - e; m = m > 4 ? 4 : m;
        unsigned p0 = packed[e];
        unsigned p1 = (m > 1) ? packed[e + 1] : 0;
        unsigned p2 = (m > 2) ? packed[e + 2] : 0;
        unsigned p3 = (m > 3) ? packed[e + 3] : 0;
        int pos0 = atomicAdd(&cnt_s[p0 >> 17], 1);
        col[e0 + pos0] = (int)(p0 & 0x1FFFFu);
        if (m > 1) { int pos = atomicAdd(&cnt_s[p1 >> 17], 1); col[e0 + pos] = (int)(p1 & 0x1FFFFu); }
        if (m > 2) { int pos = atomicAdd(&cnt_s[p2 >> 17], 1); col[e0 + pos] = (int)(p2 & 0x1FFFFu); }
        if (m > 3) { int pos = atomicAdd(&cnt_s[p3 >> 17], 1); col[e0 + pos] = (int)(p3 & 0x1FFFFu); }
    }
}

// ---- GEMM via MFMA: g16[row] = bf16( (X[row] @ W) * dis[row] ) ------------
__global__ void __launch_bounds__(256) k_gemm_mfma(const float* __restrict__ X,
                                                   const float* __restrict__ W,
                                                   const float* __restrict__ dis,
                                                   unsigned short* __restrict__ g16,
                                                   int n, int nstrips) {
    __shared__ float Ws[4096];     // 64x64 fp32 = 16 KB
    int t = threadIdx.x;
    {
        const float4* W4 = (const float4*)W;
        float4* S4 = (float4*)Ws;
#pragma unroll
        for (int i = 0; i < 4; ++i) S4[t + i * 256] = W4[t + i * 256];
    }
    __syncthreads();
    int wid  = t >> 6;
    int lane = t & 63;
    int quad = lane >> 4;
    int fl   = lane & 15;

    bf16x8 Bh[4][2], Bl[4][2];
#pragma unroll
    for (int tt = 0; tt < 4; ++tt)
#pragma unroll
        for (int c = 0; c < 2; ++c)
#pragma unroll
            for (int j = 0; j < 8; ++j) {
                float w = Ws[(c * 32 + quad * 8 + j) * 64 + tt * 16 + fl];
                short hi, lo;
                splitbf(w, hi, lo);
                Bh[tt][c][j] = hi;
                Bl[tt][c][j] = lo;
            }

    for (int s = blockIdx.x * 4 + wid; s < nstrips; s += gridDim.x * 4) {
        int row0 = s << 4;
        const float4* xp = (const float4*)(X + ((size_t)(row0 + fl) << 6));
        bf16x8 Ah[2], Al[2];
#pragma unroll
        for (int c = 0; c < 2; ++c) {
            float4 a = xp[c * 8 + quad * 2];
            float4 b = xp[c * 8 + quad * 2 + 1];
            float xs[8] = {a.x, a.y, a.z, a.w, b.x, b.y, b.z, b.w};
#pragma unroll
            for (int j = 0; j < 8; ++j) {
                short hi, lo;
                splitbf(xs[j], hi, lo);
                Ah[c][j] = hi;
                Al[c][j] = lo;
            }
        }
        f32x4 acc[4];
#pragma unroll
        for (int tt = 0; tt < 4; ++tt) acc[tt] = (f32x4){0.f, 0.f, 0.f, 0.f};
#pragma unroll
        for (int tt = 0; tt < 4; ++tt) {
#pragma unroll
            for (int c = 0; c < 2; ++c) {
                acc[tt] = __builtin_amdgcn_mfma_f32_16x16x32_bf16(Ah[c], Bh[tt][c], acc[tt], 0, 0, 0);
                acc[tt] = __builtin_amdgcn_mfma_f32_16x16x32_bf16(Al[c], Bh[tt][c], acc[tt], 0, 0, 0);
                acc[tt] = __builtin_amdgcn_mfma_f32_16x16x32_bf16(Ah[c], Bl[tt][c], acc[tt], 0, 0, 0);
            }
        }
        float4 dv = *(const float4*)(dis + row0 + quad * 4);
        float ds4[4] = {dv.x, dv.y, dv.z, dv.w};
#pragma unroll
        for (int tt = 0; tt < 4; ++tt) {
#pragma unroll
            for (int r = 0; r < 4; ++r) {
                int row = row0 + quad * 4 + r;
                float v = acc[tt][r] * ds4[r];
                g16[(size_t)row * 64 + tt * 16 + fl] = f2b(v);
            }
        }
    }
}

// ---- Aggregate (layer 2): 4-pass feature-split gather ---------------------
// Pass p touches a 32B slice of each g16 row (3.2 MB total -> L2-resident).
// Per-feature accumulation order identical to R3 (A=self-init, i&3->ABCD,
// (A+B)+(C+D)) -> bitwise-identical results.
__global__ void __launch_bounds__(256) k_agg(const unsigned short* __restrict__ g16,
                                             const int* __restrict__ col,
                                             const int* __restrict__ rp,
                                             const int* __restrict__ dega,
                                             const float* __restrict__ dis,
                                             const float* __restrict__ bias,
                                             float* __restrict__ out, int n) {
    int lane = threadIdx.x & 63;
    int wv = (blockIdx.x << 2) | (threadIdx.x >> 6);   // global wave id
    int sub = lane >> 3;               // 0..7 : node within wave
    int fl  = lane & 7;                // 0..7 : dword within 32B slice
    int base = wv << 3;
    if (base >= n) return;             // wave-uniform
    int node = base + sub;
    int nd = min(node, n - 1);
    int start = rp[nd];
    int deg = (node < n) ? dega[nd] : 0;
    int dm = max(deg, __shfl_xor(deg, 8));
    dm = max(dm, __shfl_xor(dm, 16));
    dm = max(dm, __shfl_xor(dm, 32));  // wave max deg
    float s = dis[nd];
    const unsigned* g16u = (const unsigned*)g16;   // row stride 32 uints
    int sb = sub << 3;

#pragma unroll 1
    for (int p = 0; p < 4; ++p) {
        unsigned us = g16u[(size_t)nd * 32 + p * 8 + fl];   // self slice
        float A0 = blo(us), A1 = bhi(us);
        float B0 = 0.f, B1 = 0.f, C0 = 0.f, C1 = 0.f, D0 = 0.f, D1 = 0.f;
        for (int c = 0; c < dm; c += 8) {
            int rem = deg - c;
            int cv = 0;
            if (fl < rem) cv = __builtin_nontemporal_load(col + start + c + fl);
            int rr[8];
#pragma unroll
            for (int i = 0; i < 8; ++i) rr[i] = __shfl(cv, sb + i);
            unsigned u[8];
#pragma unroll
            for (int i = 0; i < 8; ++i)
                if (i < rem) u[i] = g16u[(size_t)rr[i] * 32 + p * 8 + fl];
#pragma unroll
            for (int i = 0; i < 8; ++i) {
                if (i < rem) {
                    if ((i & 3) == 0)      { A0 += blo(u[i]); A1 += bhi(u[i]); }
                    else if ((i & 3) == 1) { B0 += blo(u[i]); B1 += bhi(u[i]); }
                    else if ((i & 3) == 2) { C0 += blo(u[i]); C1 += bhi(u[i]); }
                    else                   { D0 += blo(u[i]); D1 += bhi(u[i]); }
                }
            }
        }
        float r0 = (A0 + B0) + (C0 + D0);
        float r1 = (A1 + B1) + (C1 + D1);
        f32x2 bv = *(const f32x2*)(bias + p * 16 + fl * 2);
        f32x2 o;
        o[0] = fmaf(s, r0, bv[0]);
        o[1] = fmaf(s, r1, bv[1]);
        if (node < n)
            __builtin_nontemporal_store(o, (f32x2*)(out + ((size_t)node << 6) + p * 16 + fl * 2));
    }
}

// ---- Fused agg(L1,4-pass)+relu -> LDS -> MFMA (h @ W2) * dis -> bf16 ------
// Gather identical to k_agg's 4-pass scheme; each pass writes its 2 h-feats
// per lane into hs. Epilogue (R3 verbatim): 4 waves compute 32x64 h@W2 with
// 12 MFMAs each, split-bf16x3 -> bit-identical tile math.
__global__ void __launch_bounds__(256, 4) k_agg_gemm2(const unsigned short* __restrict__ g16,
                                                      const int* __restrict__ col,
                                                      const int* __restrict__ rp,
                                                      const int* __restrict__ dega,
                                                      const float* __restrict__ dis,
                                                      const float* __restrict__ bias,
                                                      const float* __restrict__ W2,
                                                      unsigned short* __restrict__ g16b,
                                                      int n) {
    __shared__ float W2s[4096];        // 64x64 fp32 = 16 KB
    __shared__ float hs[32 * 68];      // 32 h rows, stride 68, 8.7 KB
    int t = threadIdx.x;
    {
        const float4* W4 = (const float4*)W2;
        float4* S4 = (float4*)W2s;
#pragma unroll
        for (int i = 0; i < 4; ++i) S4[t + i * 256] = W4[t + i * 256];
    }
    // (W2s consumed only after the __syncthreads below)

    int lane = t & 63;
    int wid  = t >> 6;
    int wv = (blockIdx.x << 2) | wid;
    int sub = lane >> 3;               // 0..7 : node within wave
    int fl  = lane & 7;                // 0..7 : dword within 32B slice
    int base = wv << 3;
    int node = base + sub;
    int nd = (node < n) ? node : (n - 1);
    int start = rp[nd];
    int deg = (node < n) ? dega[nd] : 0;
    int dm = max(deg, __shfl_xor(deg, 8));
    dm = max(dm, __shfl_xor(dm, 16));
    dm = max(dm, __shfl_xor(dm, 32));  // wave max deg (0 for fully-inactive)
    float s = dis[nd];
    const unsigned* g16u = (const unsigned*)g16;
    int sb = sub << 3;
    int lrow = (wid << 3) | sub;       // 0..31 block-local row

#pragma unroll 1
    for (int p = 0; p < 4; ++p) {
        unsigned us = g16u[(size_t)nd * 32 + p * 8 + fl];   // self slice
        float A0 = blo(us), A1 = bhi(us);
        float B0 = 0.f, B1 = 0.f, C0 = 0.f, C1 = 0.f, D0 = 0.f, D1 = 0.f;
        for (int c = 0; c < dm; c += 8) {
            int rem = deg - c;
            int cv = 0;
            if (fl < rem) cv = __builtin_nontemporal_load(col + start + c + fl);
            int rr[8];
#pragma unroll
            for (int i = 0; i < 8; ++i) rr[i] = __shfl(cv, sb + i);
            unsigned u[8];
#pragma unroll
            for (int i = 0; i < 8; ++i)
                if (i < rem) u[i] = g16u[(size_t)rr[i] * 32 + p * 8 + fl];
#pragma unroll
            for (int i = 0; i < 8; ++i) {
                if (i < rem) {
                    if ((i & 3) == 0)      { A0 += blo(u[i]); A1 += bhi(u[i]); }
                    else if ((i & 3) == 1) { B0 += blo(u[i]); B1 += bhi(u[i]); }
                    else if ((i & 3) == 2) { C0 += blo(u[i]); C1 += bhi(u[i]); }
                    else                   { D0 += blo(u[i]); D1 += bhi(u[i]); }
                }
            }
        }
        float r0 = (A0 + B0) + (C0 + D0);
        float r1 = (A1 + B1) + (C1 + D1);
        f32x2 bv = *(const f32x2*)(bias + p * 16 + fl * 2);
        f32x2 h2;
        if (node < n) {
            h2[0] = fmaxf(fmaf(s, r0, bv[0]), 0.f);
            h2[1] = fmaxf(fmaf(s, r1, bv[1]), 0.f);
        } else {
            h2[0] = 0.f;
            h2[1] = 0.f;
        }
        *(f32x2*)&hs[lrow * 68 + p * 16 + fl * 2] = h2;
    }
    __syncthreads();

    // ---- MFMA epilogue: 32x64 = hs @ W2s, 2 row-strips x 4 col-tiles ------
    {
        int quad = lane >> 4;
        int fq   = lane & 15;
        int strip = wid >> 1;          // 0/1 : 16-row strip
        int tbase = (wid & 1) << 1;    // col tiles tbase, tbase+1
        bf16x8 Ah[2], Al[2];
#pragma unroll
        for (int kc = 0; kc < 2; ++kc) {
            const float* hp2 = &hs[(strip * 16 + fq) * 68 + kc * 32 + quad * 8];
            float4 a = *(const float4*)hp2;
            float4 b = *(const float4*)(hp2 + 4);
            float xs[8] = {a.x, a.y, a.z, a.w, b.x, b.y, b.z, b.w};
#pragma unroll
            for (int j = 0; j < 8; ++j) {
                short hi, lo;
                splitbf(xs[j], hi, lo);
                Ah[kc][j] = hi;
                Al[kc][j] = lo;
            }
        }
        f32x4 acc[2];
        acc[0] = (f32x4){0.f, 0.f, 0.f, 0.f};
        acc[1] = (f32x4){0.f, 0.f, 0.f, 0.f};
#pragma unroll
        for (int tt = 0; tt < 2; ++tt) {
#pragma unroll
            for (int kc = 0; kc < 2; ++kc) {
                bf16x8 Bh, Bl;
#pragma unroll
                for (int j = 0; j < 8; ++j) {
                    float w = W2s[(kc * 32 + quad * 8 + j) * 64 + (tbase + tt) * 16 + fq];
                    short hi, lo;
                    splitbf(w, hi, lo);
                    Bh[j] = hi;
                    Bl[j] = lo;
                }
                acc[tt] = __builtin_amdgcn_mfma_f32_16x16x32_bf16(Ah[kc], Bh, acc[tt], 0, 0, 0);
                acc[tt] = __builtin_amdgcn_mfma_f32_16x16x32_bf16(Al[kc], Bh, acc[tt], 0, 0, 0);
                acc[tt] = __builtin_amdgcn_mfma_f32_16x16x32_bf16(Ah[kc], Bl, acc[tt], 0, 0, 0);
            }
        }
        int row0 = (blockIdx.x << 5) + strip * 16 + quad * 4;
        float d4[4];
        if (row0 + 3 < n) {
            float4 dv = *(const float4*)(dis + row0);
            d4[0] = dv.x; d4[1] = dv.y; d4[2] = dv.z; d4[3] = dv.w;
        } else {
#pragma unroll
            for (int r2 = 0; r2 < 4; ++r2) d4[r2] = (row0 + r2 < n) ? dis[row0 + r2] : 0.f;
        }
#pragma unroll
        for (int tt = 0; tt < 2; ++tt) {
#pragma unroll
            for (int r2 = 0; r2 < 4; ++r2) {
                int row = row0 + r2;
                if (row < n)
                    g16b[(size_t)row * 64 + (tbase + tt) * 16 + fq] = f2b(acc[tt][r2] * d4[r2]);
            }
        }
    }
}

extern "C" void kernel_launch(void* const* d_in, const int* in_sizes, int n_in,
                              void* d_out, int out_size, void* d_ws, size_t ws_size,
                              hipStream_t stream) {
    const float* x  = (const float*)d_in[0];
    const int*   ei = (const int*)d_in[1];
    const float* W1 = (const float*)d_in[2];
    const float* b1 = (const float*)d_in[3];
    const float* W2 = (const float*)d_in[4];
    const float* b2 = (const float*)d_in[5];
    float* out = (float*)d_out;

    const int N = in_sizes[0] / 64;
    const int E = in_sizes[1] / 2;
    const int NB = (N + BK_NODES - 1) >> BK_SHIFT;
    const int nstrips = (N + 15) >> 4;
    const int* src = ei;
    const int* dst = ei + E;

    char* ws = (char*)d_ws;
    size_t off = 0;
    auto alloc = [&](size_t bytes) -> void* {
        void* p = ws + off;
        off = (off + bytes + 255) & ~(size_t)255;
        return p;
    };
    int*            gcursor = (int*)alloc((size_t)NB * 4);
    int*            rp      = (int*)alloc((size_t)N * 4);
    int*            dega    = (int*)alloc((size_t)N * 4);
    float*          dis     = (float*)alloc((size_t)N * 4);
    unsigned*       packed  = (unsigned*)alloc((size_t)NB * CAP * 4);
    int*            col     = (int*)alloc((size_t)NB * CAP * 4);
    unsigned short* g16     = (unsigned short*)alloc((size_t)N * 64 * 2);
    unsigned short* g16b    = (unsigned short*)alloc((size_t)N * 64 * 2);
    (void)ws_size;

    k_init<<<1, 256, 0, stream>>>(gcursor, NB);
    k_bscatter<<<(E + EPB - 1) / EPB, 256, 0, stream>>>(src, dst, gcursor, packed, E, NB);
    k_build<<<NB, 512, 0, stream>>>(packed, gcursor, rp, dega, dis, col, N);

    // Layer 1 GEMM (MFMA), fused agg1+relu+GEMM2 -> g16b, then agg2 -> out
    k_gemm_mfma<<<782, 256, 0, stream>>>(x, W1, dis, g16, N, nstrips);
    k_agg_gemm2<<<(N + 31) / 32, 256, 0, stream>>>(g16, col, rp, dega, dis, b1, W2, g16b, N);
    k_agg<<<(N + 31) / 32, 256, 0, stream>>>(g16b, col, rp, dega, dis, b2, out, N);
}

// Round 9
// 290.878 us; speedup vs baseline: 5.3769x; 1.1530x over previous
//
#include <hip/hip_runtime.h>
#include <cstdint>
#include <cstddef>

// ---------------------------------------------------------------------------
// GCN 2-layer, N=100k nodes, E=1.6M edges, F=64, fp32 in/out.
//
//   deg[n]  built by k_escatter (global int atomics, single pass)
//   dis(n) = rsqrt(deg+1) recomputed at use (bitwise-identical everywhere)
//   g   = bf16( (X @ W1) * dis[row] )   GEMM via MFMA, split-bf16 x3
//   h   = relu( dis * (gather g) + b1 ) R3 gather (best measured)
//   g'  = bf16( (h @ W2) * dis )        fused MFMA epilogue (R3)
//   out = dis * (gather g') + b2        R3 gather
//
// R9: CSR pipeline (init+bscatter+build, ~3 kernels and the packed array)
// replaced by ONE single-pass kernel writing 64-slot padded per-node
// windows: pos = atomicAdd(&deg[dst]) ; col[dst*64+pos] = src.
// Poisson(16) -> P(deg>=64) ~ 3e-22: padding is safe. Edge order within a
// node = atomic arrival order (same nondeterminism class as the old build
// pass 2; R5/R6 full reorders gave identical absmax).
// R8 lesson (permanent): L2 footprint is LINE-granular -- a 128B row is one
// line, so feature-split passes multiply misses (FETCH 83->326MB, 4x).
// Agg is L2-miss-traffic bound at ~2TB/s LLC random-line rate; 43us/agg is
// near structural. R5/R6: LDS fp32 atomics = CAS storm, abandoned.
// R2: no manual gather pipelining. R1: keep agg VGPR low.
// ---------------------------------------------------------------------------

typedef short bf16x8 __attribute__((ext_vector_type(8)));
typedef float f32x4  __attribute__((ext_vector_type(4)));

static __device__ __forceinline__ unsigned short f2b(float f) {
    unsigned x = __float_as_uint(f);
    unsigned r = (x + 0x7FFFu + ((x >> 16) & 1u)) >> 16;   // RNE
    return (unsigned short)r;
}
static __device__ __forceinline__ float blo(unsigned u) {
    return __uint_as_float(u << 16);
}
static __device__ __forceinline__ float bhi(unsigned u) {
    return __uint_as_float(u & 0xFFFF0000u);
}
static __device__ __forceinline__ void splitbf(float x, short& hi, short& lo) {
    unsigned short h = f2b(x);
    hi = (short)h;
    float r = x - __uint_as_float((unsigned)h << 16);
    lo = (short)f2b(r);
}

// ---- single-pass CSR into 64-slot padded per-node windows -----------------
// deg[] zero-initialized. 8 edges/thread: batched loads, 8 atomics in
// flight, then 8 dependent scattered stores.
__global__ void __launch_bounds__(256) k_escatter(const int* __restrict__ src,
                                                  const int* __restrict__ dst,
                                                  int* __restrict__ deg,
                                                  int* __restrict__ col, int E) {
    int e0 = (blockIdx.x * 256 + threadIdx.x) * 8;
    if (e0 + 7 < E) {
        int4 d0 = *(const int4*)(dst + e0);
        int4 d1 = *(const int4*)(dst + e0 + 4);
        int4 s0 = *(const int4*)(src + e0);
        int4 s1 = *(const int4*)(src + e0 + 4);
        int p0 = atomicAdd(deg + d0.x, 1);
        int p1 = atomicAdd(deg + d0.y, 1);
        int p2 = atomicAdd(deg + d0.z, 1);
        int p3 = atomicAdd(deg + d0.w, 1);
        int p4 = atomicAdd(deg + d1.x, 1);
        int p5 = atomicAdd(deg + d1.y, 1);
        int p6 = atomicAdd(deg + d1.z, 1);
        int p7 = atomicAdd(deg + d1.w, 1);
        col[(d0.x << 6) + p0] = s0.x;
        col[(d0.y << 6) + p1] = s0.y;
        col[(d0.z << 6) + p2] = s0.z;
        col[(d0.w << 6) + p3] = s0.w;
        col[(d1.x << 6) + p4] = s1.x;
        col[(d1.y << 6) + p5] = s1.y;
        col[(d1.z << 6) + p6] = s1.z;
        col[(d1.w << 6) + p7] = s1.w;
    } else {
        for (int e = e0; e < E; ++e) {
            int d = dst[e];
            int p = atomicAdd(deg + d, 1);
            col[(d << 6) + p] = src[e];
        }
    }
}

// ---- GEMM via MFMA: g16[row] = bf16( (X[row] @ W) * rsqrt(deg+1) ) --------
// Layouts (measured, learn_hip m89/m91/m120):
//   A[m=lane&15][k=quad*8+j]   B[k=quad*8+j][n=lane&15]
//   C: col=lane&15, row=quad*4+reg
__global__ void __launch_bounds__(256) k_gemm_mfma(const float* __restrict__ X,
                                                   const float* __restrict__ W,
                                                   const int* __restrict__ deg,
                                                   unsigned short* __restrict__ g16,
                                                   int n, int nstrips) {
    __shared__ float Ws[4096];     // 64x64 fp32 = 16 KB
    int t = threadIdx.x;
    {
        const float4* W4 = (const float4*)W;
        float4* S4 = (float4*)Ws;
#pragma unroll
        for (int i = 0; i < 4; ++i) S4[t + i * 256] = W4[t + i * 256];
    }
    __syncthreads();
    int wid  = t >> 6;
    int lane = t & 63;
    int quad = lane >> 4;
    int fl   = lane & 15;

    bf16x8 Bh[4][2], Bl[4][2];
#pragma unroll
    for (int tt = 0; tt < 4; ++tt)
#pragma unroll
        for (int c = 0; c < 2; ++c)
#pragma unroll
            for (int j = 0; j < 8; ++j) {
                float w = Ws[(c * 32 + quad * 8 + j) * 64 + tt * 16 + fl];
                short hi, lo;
                splitbf(w, hi, lo);
                Bh[tt][c][j] = hi;
                Bl[tt][c][j] = lo;
            }

    for (int s = blockIdx.x * 4 + wid; s < nstrips; s += gridDim.x * 4) {
        int row0 = s << 4;
        const float4* xp = (const float4*)(X + ((size_t)(row0 + fl) << 6));
        bf16x8 Ah[2], Al[2];
#pragma unroll
        for (int c = 0; c < 2; ++c) {
            float4 a = xp[c * 8 + quad * 2];
            float4 b = xp[c * 8 + quad * 2 + 1];
            float xs[8] = {a.x, a.y, a.z, a.w, b.x, b.y, b.z, b.w};
#pragma unroll
            for (int j = 0; j < 8; ++j) {
                short hi, lo;
                splitbf(xs[j], hi, lo);
                Ah[c][j] = hi;
                Al[c][j] = lo;
            }
        }
        f32x4 acc[4];
#pragma unroll
        for (int tt = 0; tt < 4; ++tt) acc[tt] = (f32x4){0.f, 0.f, 0.f, 0.f};
#pragma unroll
        for (int tt = 0; tt < 4; ++tt) {
#pragma unroll
            for (int c = 0; c < 2; ++c) {
                acc[tt] = __builtin_amdgcn_mfma_f32_16x16x32_bf16(Ah[c], Bh[tt][c], acc[tt], 0, 0, 0);
                acc[tt] = __builtin_amdgcn_mfma_f32_16x16x32_bf16(Al[c], Bh[tt][c], acc[tt], 0, 0, 0);
                acc[tt] = __builtin_amdgcn_mfma_f32_16x16x32_bf16(Ah[c], Bl[tt][c], acc[tt], 0, 0, 0);
            }
        }
        int4 dvi = *(const int4*)(deg + row0 + quad * 4);
        float ds4[4] = {rsqrtf((float)(dvi.x + 1)), rsqrtf((float)(dvi.y + 1)),
                        rsqrtf((float)(dvi.z + 1)), rsqrtf((float)(dvi.w + 1))};
#pragma unroll
        for (int tt = 0; tt < 4; ++tt) {
#pragma unroll
            for (int r = 0; r < 4; ++r) {
                int row = row0 + quad * 4 + r;
                float v = acc[tt][r] * ds4[r];
                g16[(size_t)row * 64 + tt * 16 + fl] = f2b(v);
            }
        }
    }
}

// ---- Aggregate (layer 2): R3 gather, per-node windows ---------------------
// 8 nodes/wave, 8 lanes x uint4 per node, 8 row-loads in flight.
__global__ void __launch_bounds__(256) k_agg(const unsigned short* __restrict__ g16,
                                             const int* __restrict__ col,
                                             const int* __restrict__ deg,
                                             const float* __restrict__ bias,
                                             float* __restrict__ out, int n) {
    int lane = threadIdx.x & 63;
    int wv = (blockIdx.x << 2) | (threadIdx.x >> 6);   // global wave id
    int sub = lane >> 3;               // 0..7 : node within wave
    int fl  = lane & 7;                // 0..7 : 8-feat group
    int base = wv << 3;
    if (base >= n) return;             // wave-uniform
    int node = base + sub;
    int nd = min(node, n - 1);
    int start = nd << 6;               // 64-slot padded window
    int dg = (node < n) ? deg[nd] : 0;
    int dm = max(dg, __shfl_xor(dg, 8));
    dm = max(dm, __shfl_xor(dm, 16));
    dm = max(dm, __shfl_xor(dm, 32));  // wave max deg

    uint4 us = *((const uint4*)(g16 + ((size_t)nd << 6)) + fl);   // self row
    float A[8], B[8], C[8], D[8];
    A[0] = blo(us.x); A[1] = bhi(us.x); A[2] = blo(us.y); A[3] = bhi(us.y);
    A[4] = blo(us.z); A[5] = bhi(us.z); A[6] = blo(us.w); A[7] = bhi(us.w);
#pragma unroll
    for (int j = 0; j < 8; ++j) { B[j] = 0.f; C[j] = 0.f; D[j] = 0.f; }

    int sb = sub << 3;
    for (int c = 0; c < dm; c += 8) {
        int rem = dg - c;
        int cv = 0;
        if (fl < rem) cv = col[start + c + fl];
        int rr[8];
#pragma unroll
        for (int i = 0; i < 8; ++i) rr[i] = __shfl(cv, sb + i);
        uint4 u[8];
#pragma unroll
        for (int i = 0; i < 8; ++i)
            if (i < rem) u[i] = *((const uint4*)(g16 + ((size_t)rr[i] << 6)) + fl);
#pragma unroll
        for (int i = 0; i < 8; ++i) {
            if (i < rem) {
                float* T = ((i & 3) == 0) ? A : ((i & 3) == 1) ? B : ((i & 3) == 2) ? C : D;
                T[0] += blo(u[i].x); T[1] += bhi(u[i].x);
                T[2] += blo(u[i].y); T[3] += bhi(u[i].y);
                T[4] += blo(u[i].z); T[5] += bhi(u[i].z);
                T[6] += blo(u[i].w); T[7] += bhi(u[i].w);
            }
        }
    }
    float s = rsqrtf((float)(dg + 1));
    float4 bv0 = ((const float4*)bias)[fl * 2];
    float4 bv1 = ((const float4*)bias)[fl * 2 + 1];
    float r[8];
#pragma unroll
    for (int j = 0; j < 8; ++j) r[j] = (A[j] + B[j]) + (C[j] + D[j]);
    float4 o0, o1;
    o0.x = fmaf(s, r[0], bv0.x); o0.y = fmaf(s, r[1], bv0.y);
    o0.z = fmaf(s, r[2], bv0.z); o0.w = fmaf(s, r[3], bv0.w);
    o1.x = fmaf(s, r[4], bv1.x); o1.y = fmaf(s, r[5], bv1.y);
    o1.z = fmaf(s, r[6], bv1.z); o1.w = fmaf(s, r[7], bv1.w);
    if (node < n) {
        float4* op = (float4*)(out + ((size_t)node << 6)) + fl * 2;
        op[0] = o0;
        op[1] = o1;
    }
}

// ---- Fused agg(L1)+relu -> LDS -> MFMA (h @ W2) * dis -> bf16 (R3) --------
__global__ void __launch_bounds__(256, 4) k_agg_gemm2(const unsigned short* __restrict__ g16,
                                                      const int* __restrict__ col,
                                                      const int* __restrict__ deg,
                                                      const float* __restrict__ bias,
                                                      const float* __restrict__ W2,
                                                      unsigned short* __restrict__ g16b,
                                                      int n) {
    __shared__ float W2s[4096];        // 64x64 fp32 = 16 KB
    __shared__ float hs[32 * 68];      // 32 h rows, stride 68, 8.7 KB
    int t = threadIdx.x;
    {
        const float4* W4 = (const float4*)W2;
        float4* S4 = (float4*)W2s;
#pragma unroll
        for (int i = 0; i < 4; ++i) S4[t + i * 256] = W4[t + i * 256];
    }
    // (W2s consumed only after the __syncthreads below)

    int lane = t & 63;
    int wid  = t >> 6;
    int wv = (blockIdx.x << 2) | wid;
    int sub = lane >> 3;               // 0..7 : node within wave
    int fl  = lane & 7;                // 0..7 : 8-feat group
    int base = wv << 3;
    int node = base + sub;
    int nd = (node < n) ? node : (n - 1);
    int start = nd << 6;               // 64-slot padded window
    int dg = (node < n) ? deg[nd] : 0;
    int dm = max(dg, __shfl_xor(dg, 8));
    dm = max(dm, __shfl_xor(dm, 16));
    dm = max(dm, __shfl_xor(dm, 32));  // wave max deg (0 for fully-inactive)

    uint4 us = *((const uint4*)(g16 + ((size_t)nd << 6)) + fl);   // self row
    float A[8], B[8], C[8], D[8];
    A[0] = blo(us.x); A[1] = bhi(us.x); A[2] = blo(us.y); A[3] = bhi(us.y);
    A[4] = blo(us.z); A[5] = bhi(us.z); A[6] = blo(us.w); A[7] = bhi(us.w);
#pragma unroll
    for (int j = 0; j < 8; ++j) { B[j] = 0.f; C[j] = 0.f; D[j] = 0.f; }

    int sb = sub << 3;
    for (int c = 0; c < dm; c += 8) {
        int rem = dg - c;
        int cv = 0;
        if (fl < rem) cv = col[start + c + fl];
        int rr[8];
#pragma unroll
        for (int i = 0; i < 8; ++i) rr[i] = __shfl(cv, sb + i);
        uint4 u[8];
#pragma unroll
        for (int i = 0; i < 8; ++i)
            if (i < rem) u[i] = *((const uint4*)(g16 + ((size_t)rr[i] << 6)) + fl);
#pragma unroll
        for (int i = 0; i < 8; ++i) {
            if (i < rem) {
                float* T = ((i & 3) == 0) ? A : ((i & 3) == 1) ? B : ((i & 3) == 2) ? C : D;
                T[0] += blo(u[i].x); T[1] += bhi(u[i].x);
                T[2] += blo(u[i].y); T[3] += bhi(u[i].y);
                T[4] += blo(u[i].z); T[5] += bhi(u[i].z);
                T[6] += blo(u[i].w); T[7] += bhi(u[i].w);
            }
        }
    }
    // h = relu(dis*agg + b1); this lane holds feats fl*8..fl*8+7 of its node
    {
        float s = rsqrtf((float)(dg + 1));
        float4 bv0 = ((const float4*)bias)[fl * 2];
        float4 bv1 = ((const float4*)bias)[fl * 2 + 1];
        float r[8];
#pragma unroll
        for (int j = 0; j < 8; ++j) r[j] = (A[j] + B[j]) + (C[j] + D[j]);
        float4 h0, h1;
        h0.x = fmaxf(fmaf(s, r[0], bv0.x), 0.f);
        h0.y = fmaxf(fmaf(s, r[1], bv0.y), 0.f);
        h0.z = fmaxf(fmaf(s, r[2], bv0.z), 0.f);
        h0.w = fmaxf(fmaf(s, r[3], bv0.w), 0.f);
        h1.x = fmaxf(fmaf(s, r[4], bv1.x), 0.f);
        h1.y = fmaxf(fmaf(s, r[5], bv1.y), 0.f);
        h1.z = fmaxf(fmaf(s, r[6], bv1.z), 0.f);
        h1.w = fmaxf(fmaf(s, r[7], bv1.w), 0.f);
        int lrow = (wid << 3) | sub;   // 0..31 block-local row
        float* hp = &hs[lrow * 68 + fl * 8];   // byte addr % 16 == 0
        *(float4*)hp = h0;
        *(float4*)(hp + 4) = h1;
    }
    __syncthreads();

    // ---- MFMA epilogue: 32x64 = hs @ W2s, 2 row-strips x 4 col-tiles ------
    {
        int quad = lane >> 4;
        int fq   = lane & 15;
        int strip = wid >> 1;          // 0/1 : 16-row strip
        int tbase = (wid & 1) << 1;    // col tiles tbase, tbase+1
        bf16x8 Ah[2], Al[2];
#pragma unroll
        for (int kc = 0; kc < 2; ++kc) {
            const float* hp2 = &hs[(strip * 16 + fq) * 68 + kc * 32 + quad * 8];
            float4 a = *(const float4*)hp2;
            float4 b = *(const float4*)(hp2 + 4);
            float xs[8] = {a.x, a.y, a.z, a.w, b.x, b.y, b.z, b.w};
#pragma unroll
            for (int j = 0; j < 8; ++j) {
                short hi, lo;
                splitbf(xs[j], hi, lo);
                Ah[kc][j] = hi;
                Al[kc][j] = lo;
            }
        }
        f32x4 acc[2];
        acc[0] = (f32x4){0.f, 0.f, 0.f, 0.f};
        acc[1] = (f32x4){0.f, 0.f, 0.f, 0.f};
#pragma unroll
        for (int tt = 0; tt < 2; ++tt) {
#pragma unroll
            for (int kc = 0; kc < 2; ++kc) {
                bf16x8 Bh, Bl;
#pragma unroll
                for (int j = 0; j < 8; ++j) {
                    float w = W2s[(kc * 32 + quad * 8 + j) * 64 + (tbase + tt) * 16 + fq];
                    short hi, lo;
                    splitbf(w, hi, lo);
                    Bh[j] = hi;
                    Bl[j] = lo;
                }
                acc[tt] = __builtin_amdgcn_mfma_f32_16x16x32_bf16(Ah[kc], Bh, acc[tt], 0, 0, 0);
                acc[tt] = __builtin_amdgcn_mfma_f32_16x16x32_bf16(Al[kc], Bh, acc[tt], 0, 0, 0);
                acc[tt] = __builtin_amdgcn_mfma_f32_16x16x32_bf16(Ah[kc], Bl, acc[tt], 0, 0, 0);
            }
        }
        int row0 = (blockIdx.x << 5) + strip * 16 + quad * 4;
        float d4[4];
#pragma unroll
        for (int r2 = 0; r2 < 4; ++r2)
            d4[r2] = (row0 + r2 < n) ? rsqrtf((float)(deg[row0 + r2] + 1)) : 0.f;
#pragma unroll
        for (int tt = 0; tt < 2; ++tt) {
#pragma unroll
            for (int r2 = 0; r2 < 4; ++r2) {
                int row = row0 + r2;
                if (row < n)
                    g16b[(size_t)row * 64 + (tbase + tt) * 16 + fq] = f2b(acc[tt][r2] * d4[r2]);
            }
        }
    }
}

extern "C" void kernel_launch(void* const* d_in, const int* in_sizes, int n_in,
                              void* d_out, int out_size, void* d_ws, size_t ws_size,
                              hipStream_t stream) {
    const float* x  = (const float*)d_in[0];
    const int*   ei = (const int*)d_in[1];
    const float* W1 = (const float*)d_in[2];
    const float* b1 = (const float*)d_in[3];
    const float* W2 = (const float*)d_in[4];
    const float* b2 = (const float*)d_in[5];
    float* out = (float*)d_out;

    const int N = in_sizes[0] / 64;
    const int E = in_sizes[1] / 2;
    const int nstrips = (N + 15) >> 4;
    const int* src = ei;
    const int* dst = ei + E;

    char* ws = (char*)d_ws;
    size_t off = 0;
    auto alloc = [&](size_t bytes) -> void* {
        void* p = ws + off;
        off = (off + bytes + 255) & ~(size_t)255;
        return p;
    };
    int*            deg  = (int*)alloc((size_t)N * 4);
    int*            col  = (int*)alloc((size_t)N * 64 * 4);   // 64-slot windows
    unsigned short* g16  = (unsigned short*)alloc((size_t)N * 64 * 2);
    unsigned short* g16b = (unsigned short*)alloc((size_t)N * 64 * 2);
    (void)ws_size;

    hipMemsetAsync(deg, 0, (size_t)N * 4, stream);
    k_escatter<<<(E + 2047) / 2048, 256, 0, stream>>>(src, dst, deg, col, E);
    k_gemm_mfma<<<782, 256, 0, stream>>>(x, W1, deg, g16, N, nstrips);
    k_agg_gemm2<<<(N + 31) / 32, 256, 0, stream>>>(g16, col, deg, b1, W2, g16b, N);
    k_agg<<<(N + 31) / 32, 256, 0, stream>>>(g16b, col, deg, b2, out, N);
}

// Round 10
// 199.660 us; speedup vs baseline: 7.8334x; 1.4569x over previous
//
#include <hip/hip_runtime.h>
#include <cstdint>
#include <cstddef>

// ---------------------------------------------------------------------------
// GCN 2-layer, N=100k nodes, E=1.6M edges, F=64, fp32 in/out.
//
//   dis[n] = rsqrt(in_deg[n]+1)            (self-loop folded in analytically)
//   g = bf16( (X @ W1) * dis[row] )        GEMM via MFMA, split-bf16 x3
//   h = relu( dis * (gather-sum g) + b1 )  R3 gather (best measured)
//   g' = bf16( (h @ W2) * dis )            fused MFMA epilogue in agg1 (R3)
//   out = dis * (gather-sum g') + b2       R3 gather
//
// R10 = R3 (199.3 us, best measured) with ONLY k_build changed:
//  - bucket window LDS-staged once (48 KB) -> second 6.4 MB global read gone
//  - Hillis-Steele scan (18 barriers) -> shfl wave-scan (2 barriers)
// Session ledger: R8: L2 footprint is LINE-granular (feature-split = 4x
// FETCH). R9: scattered 4B stores are line-granular too (15x write amp) and
// returning-atomic chains are latency-bound -> single-pass CSR abandoned.
// R5/R6: LDS fp32 atomics = CAS storm at HIP level. R2: no manual gather
// pipelining. R1: keep agg VGPR low. Aggs (~43 us each) are L2-miss
// random-line bound (time = FETCH / ~2 TB/s) -- structural.
// ---------------------------------------------------------------------------

#define BK_SHIFT 9                 // 512 nodes per bucket
#define BK_NODES 512
#define EPB 8192                   // edges per scatter block
#define CAP 12288                  // padded bucket capacity (slots)
#define NBMAX 256                  // max buckets (N<=131072 -> NB<=256)

typedef short bf16x8 __attribute__((ext_vector_type(8)));
typedef float f32x4  __attribute__((ext_vector_type(4)));

static __device__ __forceinline__ unsigned short f2b(float f) {
    unsigned x = __float_as_uint(f);
    unsigned r = (x + 0x7FFFu + ((x >> 16) & 1u)) >> 16;   // RNE
    return (unsigned short)r;
}
static __device__ __forceinline__ float blo(unsigned u) {
    return __uint_as_float(u << 16);
}
static __device__ __forceinline__ float bhi(unsigned u) {
    return __uint_as_float(u & 0xFFFF0000u);
}
static __device__ __forceinline__ void splitbf(float x, short& hi, short& lo) {
    unsigned short h = f2b(x);
    hi = (short)h;
    float r = x - __uint_as_float((unsigned)h << 16);
    lo = (short)f2b(r);
}

// ---- init: gcursor[b] = b*CAP --------------------------------------------
__global__ void k_init(int* __restrict__ gcursor, int NB) {
    int t = threadIdx.x;
    if (t < NB) gcursor[t] = t * CAP;
}

// ---- scatter edges into padded bucket windows, packed uint32 --------------
// pack = src (17 bits) | dst_local (9 bits) << 17   (N <= 131072)
__global__ void __launch_bounds__(256) k_bscatter(const int* __restrict__ src,
                                                  const int* __restrict__ dst,
                                                  int* __restrict__ gcursor,
                                                  unsigned* __restrict__ packed,
                                                  int E, int NB) {
    __shared__ int hist[NBMAX];
    __shared__ int base[NBMAX];
    int t = threadIdx.x;
    for (int i = t; i < NB; i += 256) hist[i] = 0;
    __syncthreads();
    int e0 = blockIdx.x * EPB;
    int e1 = min(e0 + EPB, E);
    int4 dv[8];
    int kd[8];
#pragma unroll
    for (int k = 0; k < 8; ++k) {
        int e = e0 + t * 4 + k * 1024;
        kd[k] = (e + 3 < e1) ? 1 : 0;
        if (kd[k]) dv[k] = *(const int4*)(dst + e);
    }
#pragma unroll
    for (int k = 0; k < 8; ++k) {
        if (kd[k]) {
            atomicAdd(&hist[dv[k].x >> BK_SHIFT], 1);
            atomicAdd(&hist[dv[k].y >> BK_SHIFT], 1);
            atomicAdd(&hist[dv[k].z >> BK_SHIFT], 1);
            atomicAdd(&hist[dv[k].w >> BK_SHIFT], 1);
        }
    }
    __syncthreads();
    for (int i = t; i < NB; i += 256) {
        int c = hist[i];
        base[i] = c ? atomicAdd(&gcursor[i], c) : 0;
        hist[i] = 0;
    }
    __syncthreads();
    int4 sv[8];
#pragma unroll
    for (int k = 0; k < 8; ++k) {
        int e = e0 + t * 4 + k * 1024;
        if (kd[k]) sv[k] = *(const int4*)(src + e);
    }
#pragma unroll
    for (int k = 0; k < 8; ++k) {
        if (kd[k]) {
            int b0 = dv[k].x >> BK_SHIFT;
            int p0 = base[b0] + atomicAdd(&hist[b0], 1);
            packed[p0] = (unsigned)sv[k].x | (((unsigned)dv[k].x & (BK_NODES - 1)) << 17);
            int b1 = dv[k].y >> BK_SHIFT;
            int p1 = base[b1] + atomicAdd(&hist[b1], 1);
            packed[p1] = (unsigned)sv[k].y | (((unsigned)dv[k].y & (BK_NODES - 1)) << 17);
            int b2 = dv[k].z >> BK_SHIFT;
            int p2 = base[b2] + atomicAdd(&hist[b2], 1);
            packed[p2] = (unsigned)sv[k].z | (((unsigned)dv[k].z & (BK_NODES - 1)) << 17);
            int b3 = dv[k].w >> BK_SHIFT;
            int p3 = base[b3] + atomicAdd(&hist[b3], 1);
            packed[p3] = (unsigned)sv[k].w | (((unsigned)dv[k].w & (BK_NODES - 1)) << 17);
        }
    }
}

// ---- per-bucket CSR build (one block of 512 per bucket) -------------------
// R10: window staged in LDS once (48 KB); count+scatter read LDS.
// Scan: per-wave shfl_up inclusive scan + 8-wave cross-scan (2 barriers vs
// 18 in the Hillis-Steele version).
__global__ void __launch_bounds__(512) k_build(const unsigned* __restrict__ packed,
                                               const int* __restrict__ gcursor,
                                               int* __restrict__ rp,
                                               int* __restrict__ dega,
                                               float* __restrict__ dis,
                                               int* __restrict__ col, int N) {
    __shared__ unsigned pk[CAP];       // 48 KB bucket window stage
    __shared__ int cnt_s[BK_NODES];
    __shared__ int woff[8];
    int b = blockIdx.x;
    int t = threadIdx.x;
    int lane = t & 63;
    int wid  = t >> 6;
    int node0 = b << BK_SHIFT;
    int nnode = min(BK_NODES, N - node0);
    int e0 = b * CAP;
    int count = gcursor[b] - e0;       // final cursor = e0 + count
    cnt_s[t] = 0;
    // stage window into LDS (uint4 where possible)
    for (int i = t * 4; i < count; i += 2048) {
        if (i + 3 < count) {
            *(uint4*)&pk[i] = *(const uint4*)(packed + e0 + i);
        } else {
            for (int m = i; m < count; ++m) pk[m] = packed[e0 + m];
        }
    }
    __syncthreads();
    // pass 1: count (LDS reads)
    for (int j = t; j < count; j += 512) atomicAdd(&cnt_s[pk[j] >> 17], 1);
    __syncthreads();
    // scan: wave-level shfl inclusive scan, then cross-wave offsets
    int v = cnt_s[t];
    int val = v;
#pragma unroll
    for (int off = 1; off < 64; off <<= 1) {
        int nv = __shfl_up(val, off);
        if (lane >= off) val += nv;
    }
    if (lane == 63) woff[wid] = val;   // wave total
    __syncthreads();
    if (t < 8) {
        int s = woff[t];
        int sc = s;
#pragma unroll
        for (int off = 1; off < 8; off <<= 1) {
            int nv = __shfl_up(sc, off);
            if (t >= off) sc += nv;
        }
        woff[t] = sc - s;              // exclusive wave offset
    }
    __syncthreads();
    int excl = woff[wid] + (val - v);  // exclusive prefix for node t
    if (t < nnode) {
        rp[node0 + t] = e0 + excl;
        dega[node0 + t] = v;
        dis[node0 + t] = rsqrtf((float)(v + 1));
    }
    cnt_s[t] = excl;                   // reuse as local cursor
    __syncthreads();
    // pass 2: scatter src ids into CSR order (LDS reads)
    for (int j = t; j < count; j += 512) {
        unsigned p = pk[j];
        int pos = atomicAdd(&cnt_s[p >> 17], 1);
        col[e0 + pos] = (int)(p & 0x1FFFFu);
    }
}

// ---- GEMM via MFMA: g16[row] = bf16( (X[row] @ W) * dis[row] ) ------------
// Layouts (measured, learn_hip m89/m91/m120):
//   A[m=lane&15][k=quad*8+j]   B[k=quad*8+j][n=lane&15]
//   C: col=lane&15, row=quad*4+reg
__global__ void __launch_bounds__(256) k_gemm_mfma(const float* __restrict__ X,
                                                   const float* __restrict__ W,
                                                   const float* __restrict__ dis,
                                                   unsigned short* __restrict__ g16,
                                                   int n, int nstrips) {
    __shared__ float Ws[4096];     // 64x64 fp32 = 16 KB
    int t = threadIdx.x;
    {
        const float4* W4 = (const float4*)W;
        float4* S4 = (float4*)Ws;
#pragma unroll
        for (int i = 0; i < 4; ++i) S4[t + i * 256] = W4[t + i * 256];
    }
    __syncthreads();
    int wid  = t >> 6;
    int lane = t & 63;
    int quad = lane >> 4;
    int fl   = lane & 15;

    bf16x8 Bh[4][2], Bl[4][2];
#pragma unroll
    for (int tt = 0; tt < 4; ++tt)
#pragma unroll
        for (int c = 0; c < 2; ++c)
#pragma unroll
            for (int j = 0; j < 8; ++j) {
                float w = Ws[(c * 32 + quad * 8 + j) * 64 + tt * 16 + fl];
                short hi, lo;
                splitbf(w, hi, lo);
                Bh[tt][c][j] = hi;
                Bl[tt][c][j] = lo;
            }

    for (int s = blockIdx.x * 4 + wid; s < nstrips; s += gridDim.x * 4) {
        int row0 = s << 4;
        const float4* xp = (const float4*)(X + ((size_t)(row0 + fl) << 6));
        bf16x8 Ah[2], Al[2];
#pragma unroll
        for (int c = 0; c < 2; ++c) {
            float4 a = xp[c * 8 + quad * 2];
            float4 b = xp[c * 8 + quad * 2 + 1];
            float xs[8] = {a.x, a.y, a.z, a.w, b.x, b.y, b.z, b.w};
#pragma unroll
            for (int j = 0; j < 8; ++j) {
                short hi, lo;
                splitbf(xs[j], hi, lo);
                Ah[c][j] = hi;
                Al[c][j] = lo;
            }
        }
        f32x4 acc[4];
#pragma unroll
        for (int tt = 0; tt < 4; ++tt) acc[tt] = (f32x4){0.f, 0.f, 0.f, 0.f};
#pragma unroll
        for (int tt = 0; tt < 4; ++tt) {
#pragma unroll
            for (int c = 0; c < 2; ++c) {
                acc[tt] = __builtin_amdgcn_mfma_f32_16x16x32_bf16(Ah[c], Bh[tt][c], acc[tt], 0, 0, 0);
                acc[tt] = __builtin_amdgcn_mfma_f32_16x16x32_bf16(Al[c], Bh[tt][c], acc[tt], 0, 0, 0);
                acc[tt] = __builtin_amdgcn_mfma_f32_16x16x32_bf16(Ah[c], Bl[tt][c], acc[tt], 0, 0, 0);
            }
        }
        float4 dv = *(const float4*)(dis + row0 + quad * 4);
        float ds4[4] = {dv.x, dv.y, dv.z, dv.w};
#pragma unroll
        for (int tt = 0; tt < 4; ++tt) {
#pragma unroll
            for (int r = 0; r < 4; ++r) {
                int row = row0 + quad * 4 + r;
                float v = acc[tt][r] * ds4[r];
                g16[(size_t)row * 64 + tt * 16 + fl] = f2b(v);
            }
        }
    }
}

// ---- Aggregate: 8 nodes/wave, 8 lanes x uint4 per node, 8 loads in flight -
// (exact R0/R3 structure: best-measured gather)
template <int RELU>
__global__ void __launch_bounds__(256) k_agg(const unsigned short* __restrict__ g16,
                                             const int* __restrict__ col,
                                             const int* __restrict__ rp,
                                             const int* __restrict__ dega,
                                             const float* __restrict__ dis,
                                             const float* __restrict__ bias,
                                             float* __restrict__ out, int n) {
    int lane = threadIdx.x & 63;
    int wv = (blockIdx.x << 2) | (threadIdx.x >> 6);   // global wave id
    int sub = lane >> 3;               // 0..7 : node within wave
    int fl  = lane & 7;                // 0..7 : 8-feat group
    int base = wv << 3;
    if (base >= n) return;             // wave-uniform
    int node = base + sub;
    int nd = min(node, n - 1);
    int start = rp[nd];
    int deg = (node < n) ? dega[nd] : 0;
    int dm = max(deg, __shfl_xor(deg, 8));
    dm = max(dm, __shfl_xor(dm, 16));
    dm = max(dm, __shfl_xor(dm, 32));  // wave max deg

    uint4 us = *((const uint4*)(g16 + ((size_t)nd << 6)) + fl);   // self row
    float A[8], B[8], C[8], D[8];
    A[0] = blo(us.x); A[1] = bhi(us.x); A[2] = blo(us.y); A[3] = bhi(us.y);
    A[4] = blo(us.z); A[5] = bhi(us.z); A[6] = blo(us.w); A[7] = bhi(us.w);
#pragma unroll
    for (int j = 0; j < 8; ++j) { B[j] = 0.f; C[j] = 0.f; D[j] = 0.f; }

    int sb = sub << 3;
    for (int c = 0; c < dm; c += 8) {
        int rem = deg - c;
        int cv = 0;
        if (fl < rem) cv = col[start + c + fl];
        int rr[8];
#pragma unroll
        for (int i = 0; i < 8; ++i) rr[i] = __shfl(cv, sb + i);
        uint4 u[8];
#pragma unroll
        for (int i = 0; i < 8; ++i)
            if (i < rem) u[i] = *((const uint4*)(g16 + ((size_t)rr[i] << 6)) + fl);
#pragma unroll
        for (int i = 0; i < 8; ++i) {
            if (i < rem) {
                float* T = ((i & 3) == 0) ? A : ((i & 3) == 1) ? B : ((i & 3) == 2) ? C : D;
                T[0] += blo(u[i].x); T[1] += bhi(u[i].x);
                T[2] += blo(u[i].y); T[3] += bhi(u[i].y);
                T[4] += blo(u[i].z); T[5] += bhi(u[i].z);
                T[6] += blo(u[i].w); T[7] += bhi(u[i].w);
            }
        }
    }
    float s = dis[nd];
    float4 bv0 = ((const float4*)bias)[fl * 2];
    float4 bv1 = ((const float4*)bias)[fl * 2 + 1];
    float r[8];
#pragma unroll
    for (int j = 0; j < 8; ++j) r[j] = (A[j] + B[j]) + (C[j] + D[j]);
    float4 o0, o1;
    o0.x = fmaf(s, r[0], bv0.x); o0.y = fmaf(s, r[1], bv0.y);
    o0.z = fmaf(s, r[2], bv0.z); o0.w = fmaf(s, r[3], bv0.w);
    o1.x = fmaf(s, r[4], bv1.x); o1.y = fmaf(s, r[5], bv1.y);
    o1.z = fmaf(s, r[6], bv1.z); o1.w = fmaf(s, r[7], bv1.w);
    if (RELU) {
        o0.x = fmaxf(o0.x, 0.f); o0.y = fmaxf(o0.y, 0.f);
        o0.z = fmaxf(o0.z, 0.f); o0.w = fmaxf(o0.w, 0.f);
        o1.x = fmaxf(o1.x, 0.f); o1.y = fmaxf(o1.y, 0.f);
        o1.z = fmaxf(o1.z, 0.f); o1.w = fmaxf(o1.w, 0.f);
    }
    if (node < n) {
        float4* op = (float4*)(out + ((size_t)node << 6)) + fl * 2;
        op[0] = o0;
        op[1] = o1;
    }
}

// ---- Fused aggregate(L1)+relu  ->  LDS  ->  MFMA (h @ W2) * dis -> bf16 ---
// (exact R3 kernel: best measured)
__global__ void __launch_bounds__(256, 4) k_agg_gemm2(const unsigned short* __restrict__ g16,
                                                      const int* __restrict__ col,
                                                      const int* __restrict__ rp,
                                                      const int* __restrict__ dega,
                                                      const float* __restrict__ dis,
                                                      const float* __restrict__ bias,
                                                      const float* __restrict__ W2,
                                                      unsigned short* __restrict__ g16b,
                                                      int n) {
    __shared__ float W2s[4096];        // 64x64 fp32 = 16 KB
    __shared__ float hs[32 * 68];      // 32 h rows, stride 68 (bank spread), 8.7 KB
    int t = threadIdx.x;
    {
        const float4* W4 = (const float4*)W2;
        float4* S4 = (float4*)W2s;
#pragma unroll
        for (int i = 0; i < 4; ++i) S4[t + i * 256] = W4[t + i * 256];
    }
    // (W2s consumed only after the __syncthreads below)

    int lane = t & 63;
    int wid  = t >> 6;
    int wv = (blockIdx.x << 2) | wid;
    int sub = lane >> 3;               // 0..7 : node within wave
    int fl  = lane & 7;                // 0..7 : 8-feat group
    int base = wv << 3;
    int node = base + sub;
    int nd = (node < n) ? node : (n - 1);
    int start = rp[nd];
    int deg = (node < n) ? dega[nd] : 0;
    int dm = max(deg, __shfl_xor(deg, 8));
    dm = max(dm, __shfl_xor(dm, 16));
    dm = max(dm, __shfl_xor(dm, 32));  // wave max deg (0 for fully-inactive)

    uint4 us = *((const uint4*)(g16 + ((size_t)nd << 6)) + fl);   // self row
    float A[8], B[8], C[8], D[8];
    A[0] = blo(us.x); A[1] = bhi(us.x); A[2] = blo(us.y); A[3] = bhi(us.y);
    A[4] = blo(us.z); A[5] = bhi(us.z); A[6] = blo(us.w); A[7] = bhi(us.w);
#pragma unroll
    for (int j = 0; j < 8; ++j) { B[j] = 0.f; C[j] = 0.f; D[j] = 0.f; }

    int sb = sub << 3;
    for (int c = 0; c < dm; c += 8) {
        int rem = deg - c;
        int cv = 0;
        if (fl < rem) cv = col[start + c + fl];
        int rr[8];
#pragma unroll
        for (int i = 0; i < 8; ++i) rr[i] = __shfl(cv, sb + i);
        uint4 u[8];
#pragma unroll
        for (int i = 0; i < 8; ++i)
            if (i < rem) u[i] = *((const uint4*)(g16 + ((size_t)rr[i] << 6)) + fl);
#pragma unroll
        for (int i = 0; i < 8; ++i) {
            if (i < rem) {
                float* T = ((i & 3) == 0) ? A : ((i & 3) == 1) ? B : ((i & 3) == 2) ? C : D;
                T[0] += blo(u[i].x); T[1] += bhi(u[i].x);
                T[2] += blo(u[i].y); T[3] += bhi(u[i].y);
                T[4] += blo(u[i].z); T[5] += bhi(u[i].z);
                T[6] += blo(u[i].w); T[7] += bhi(u[i].w);
            }
        }
    }
    // h = relu(dis*agg + b1); this lane holds feats fl*8..fl*8+7 of its node
    {
        float s = dis[nd];
        float4 bv0 = ((const float4*)bias)[fl * 2];
        float4 bv1 = ((const float4*)bias)[fl * 2 + 1];
        float r[8];
#pragma unroll
        for (int j = 0; j < 8; ++j) r[j] = (A[j] + B[j]) + (C[j] + D[j]);
        float4 h0, h1;
        h0.x = fmaxf(fmaf(s, r[0], bv0.x), 0.f);
        h0.y = fmaxf(fmaf(s, r[1], bv0.y), 0.f);
        h0.z = fmaxf(fmaf(s, r[2], bv0.z), 0.f);
        h0.w = fmaxf(fmaf(s, r[3], bv0.w), 0.f);
        h1.x = fmaxf(fmaf(s, r[4], bv1.x), 0.f);
        h1.y = fmaxf(fmaf(s, r[5], bv1.y), 0.f);
        h1.z = fmaxf(fmaf(s, r[6], bv1.z), 0.f);
        h1.w = fmaxf(fmaf(s, r[7], bv1.w), 0.f);
        int lrow = (wid << 3) | sub;   // 0..31 block-local row
        float* hp = &hs[lrow * 68 + fl * 8];   // byte addr % 16 == 0
        *(float4*)hp = h0;
        *(float4*)(hp + 4) = h1;
    }
    __syncthreads();

    // ---- MFMA epilogue: 32x64 = hs @ W2s, 2 row-strips x 4 col-tiles ------
    {
        int quad = lane >> 4;
        int fq   = lane & 15;
        int strip = wid >> 1;          // 0/1 : 16-row strip
        int tbase = (wid & 1) << 1;    // col tiles tbase, tbase+1
        bf16x8 Ah[2], Al[2];
#pragma unroll
        for (int kc = 0; kc < 2; ++kc) {
            const float* hp2 = &hs[(strip * 16 + fq) * 68 + kc * 32 + quad * 8];
            float4 a = *(const float4*)hp2;
            float4 b = *(const float4*)(hp2 + 4);
            float xs[8] = {a.x, a.y, a.z, a.w, b.x, b.y, b.z, b.w};
#pragma unroll
            for (int j = 0; j < 8; ++j) {
                short hi, lo;
                splitbf(xs[j], hi, lo);
                Ah[kc][j] = hi;
                Al[kc][j] = lo;
            }
        }
        f32x4 acc[2];
        acc[0] = (f32x4){0.f, 0.f, 0.f, 0.f};
        acc[1] = (f32x4){0.f, 0.f, 0.f, 0.f};
#pragma unroll
        for (int tt = 0; tt < 2; ++tt) {
#pragma unroll
            for (int kc = 0; kc < 2; ++kc) {
                bf16x8 Bh, Bl;
#pragma unroll
                for (int j = 0; j < 8; ++j) {
                    float w = W2s[(kc * 32 + quad * 8 + j) * 64 + (tbase + tt) * 16 + fq];
                    short hi, lo;
                    splitbf(w, hi, lo);
                    Bh[j] = hi;
                    Bl[j] = lo;
                }
                acc[tt] = __builtin_amdgcn_mfma_f32_16x16x32_bf16(Ah[kc], Bh, acc[tt], 0, 0, 0);
                acc[tt] = __builtin_amdgcn_mfma_f32_16x16x32_bf16(Al[kc], Bh, acc[tt], 0, 0, 0);
                acc[tt] = __builtin_amdgcn_mfma_f32_16x16x32_bf16(Ah[kc], Bl, acc[tt], 0, 0, 0);
            }
        }
        int row0 = (blockIdx.x << 5) + strip * 16 + quad * 4;
        float d4[4];
        if (row0 + 3 < n) {
            float4 dv = *(const float4*)(dis + row0);
            d4[0] = dv.x; d4[1] = dv.y; d4[2] = dv.z; d4[3] = dv.w;
        } else {
#pragma unroll
            for (int r2 = 0; r2 < 4; ++r2) d4[r2] = (row0 + r2 < n) ? dis[row0 + r2] : 0.f;
        }
#pragma unroll
        for (int tt = 0; tt < 2; ++tt) {
#pragma unroll
            for (int r2 = 0; r2 < 4; ++r2) {
                int row = row0 + r2;
                if (row < n)
                    g16b[(size_t)row * 64 + (tbase + tt) * 16 + fq] = f2b(acc[tt][r2] * d4[r2]);
            }
        }
    }
}

extern "C" void kernel_launch(void* const* d_in, const int* in_sizes, int n_in,
                              void* d_out, int out_size, void* d_ws, size_t ws_size,
                              hipStream_t stream) {
    const float* x  = (const float*)d_in[0];
    const int*   ei = (const int*)d_in[1];
    const float* W1 = (const float*)d_in[2];
    const float* b1 = (const float*)d_in[3];
    const float* W2 = (const float*)d_in[4];
    const float* b2 = (const float*)d_in[5];
    float* out = (float*)d_out;

    const int N = in_sizes[0] / 64;
    const int E = in_sizes[1] / 2;
    const int NB = (N + BK_NODES - 1) >> BK_SHIFT;
    const int nstrips = (N + 15) >> 4;
    const int* src = ei;
    const int* dst = ei + E;

    char* ws = (char*)d_ws;
    size_t off = 0;
    auto alloc = [&](size_t bytes) -> void* {
        void* p = ws + off;
        off = (off + bytes + 255) & ~(size_t)255;
        return p;
    };
    int*            gcursor = (int*)alloc((size_t)NB * 4);
    int*            rp      = (int*)alloc((size_t)N * 4);
    int*            dega    = (int*)alloc((size_t)N * 4);
    float*          dis     = (float*)alloc((size_t)N * 4);
    unsigned*       packed  = (unsigned*)alloc((size_t)NB * CAP * 4);
    int*            col     = (int*)alloc((size_t)NB * CAP * 4);
    unsigned short* g16     = (unsigned short*)alloc((size_t)N * 64 * 2);
    unsigned short* g16b    = (unsigned short*)alloc((size_t)N * 64 * 2);
    (void)ws_size;

    k_init<<<1, 256, 0, stream>>>(gcursor, NB);
    k_bscatter<<<(E + EPB - 1) / EPB, 256, 0, stream>>>(src, dst, gcursor, packed, E, NB);
    k_build<<<NB, 512, 0, stream>>>(packed, gcursor, rp, dega, dis, col, N);

    // Layer 1 GEMM (MFMA), fused agg1+relu+GEMM2 -> g16b, then agg2 -> out
    k_gemm_mfma<<<782, 256, 0, stream>>>(x, W1, dis, g16, N, nstrips);
    k_agg_gemm2<<<(N + 31) / 32, 256, 0, stream>>>(g16, col, rp, dega, dis, b1, W2, g16b, N);
    k_agg<0><<<(N + 31) / 32, 256, 0, stream>>>(g16b, col, rp, dega, dis, b2, out, N);
}